// Round 4
// baseline (1011.889 us; speedup 1.0000x reference)
//
#include <hip/hip_runtime.h>
#include <hip/hip_bf16.h>

// ConcatModel (all I/O f32; internal MFMA compute bf16, f32 accumulate):
// embed-gather(cvt) -> input-proj GEMM (pipelined) -> ONE persistent LSTM
// recurrence kernel (W_hh in VGPRs, c in VGPRs, mt-group barriers) -> feat
// -> (BN -> GEMM+ReLU) x2 -> BN -> tiny output GEMM.

typedef __attribute__((ext_vector_type(8))) short bf16x8;
typedef __attribute__((ext_vector_type(4))) float f32x4;

#define DEVI __device__ __forceinline__

template<int N> struct IC { static constexpr int v = N; };

DEVI void async16(const void* g, void* l) {
  __builtin_amdgcn_global_load_lds((const __attribute__((address_space(1))) void*)g,
                                   (__attribute__((address_space(3))) void*)l,
                                   16, 0, 0);
}
// per-wave counted wait, then align waves (tile-k loads landed collectively).
template<int N> DEVI void vmwait_barrier() {
  asm volatile("s_waitcnt vmcnt(%0)" ::"i"(N) : "memory");
  __builtin_amdgcn_s_barrier();
  __builtin_amdgcn_sched_barrier(0);
}
DEVI float sigmf_(float x) { return 1.f / (1.f + __expf(-x)); }
DEVI float tanhf_(float x) {
  float a = __expf(-2.f * fabsf(x));
  float t = (1.f - a) / (1.f + a);
  return copysignf(t, x);
}
DEVI __hip_bfloat16 f2b(float x) { return __float2bfloat16(x); }
DEVI float b2f(__hip_bfloat16 x) { return __bfloat162float(x); }

// ---------------------------------------------------------------------------
__global__ void cvt_f32_bf16(const float* __restrict__ src,
                             __hip_bfloat16* __restrict__ dst, int n4) {
  int i = blockIdx.x * 256 + threadIdx.x;
  int stride = gridDim.x * 256;
  for (; i < n4; i += stride) {
    float4 v = ((const float4*)src)[i];
    union { __hip_bfloat16 h[4]; uint2 u; } o;
    o.h[0] = f2b(v.x); o.h[1] = f2b(v.y); o.h[2] = f2b(v.z); o.h[3] = f2b(v.w);
    ((uint2*)dst)[i] = o.u;
  }
}

__global__ void pack_wih(const float* __restrict__ W_ih,
                         const float* __restrict__ b_ih,
                         const float* __restrict__ b_hh,
                         __hip_bfloat16* __restrict__ WihP,
                         float* __restrict__ biasL) {
  int tid = blockIdx.x * 256 + threadIdx.x;
  int stride = gridDim.x * 256;
  for (int i = tid; i < 2048 * 320; i += stride) {
    int r = i / 320, c = i - r * 320;
    WihP[i] = (c < 300) ? f2b(W_ih[r * 300 + c]) : f2b(0.f);
  }
  if (tid < 2048) biasL[tid] = b_ih[tid] + b_hh[tid];
}

// gather+cvt: Ain[m][0..319] bf16, m = t*512 + n; n<256 premise else hypothesis.
__global__ void gather_kernel(const int* __restrict__ prem, const int* __restrict__ hyp,
                              const float* __restrict__ embed,
                              __hip_bfloat16* __restrict__ Ain) {
  int row = blockIdx.x * 4 + (threadIdx.x >> 6);
  int lane = threadIdx.x & 63;
  int tt = row >> 9, n = row & 511;
  int tok = (n < 256) ? prem[tt * 256 + n] : hyp[tt * 256 + (n - 256)];
  const float4* e4 = (const float4*)(embed + (size_t)tok * 300);  // 75 x 16B
  uint2* d2 = (uint2*)(Ain + (size_t)row * 320);                  // 80 x 8B
  for (int j = lane; j < 75; j += 64) {
    float4 v = e4[j];
    union { __hip_bfloat16 h[4]; uint2 u; } o;
    o.h[0] = f2b(v.x); o.h[1] = f2b(v.y); o.h[2] = f2b(v.z); o.h[3] = f2b(v.w);
    d2[j] = o.u;
  }
  for (int j = 75 + lane; j < 80; j += 64) d2[j] = make_uint2(0u, 0u);
}

// ---------------------------------------------------------------------------
// Pipelined GEMM: C[M][N=128/blk] = A[M][K] * Bn[N][K]^T (+bias).
// Counted-vmcnt double-barrier K-loop + LDS-bounce coalesced epilogue.
template<int BM, int EPI>
__global__ __launch_bounds__(256)
void gemm_pipe(const __hip_bfloat16* __restrict__ A,
               const __hip_bfloat16* __restrict__ Bn,
               const float* __restrict__ bias,
               void* __restrict__ Cout, int K, int ldc) {
  constexpr int BK = 64;
  constexpr int ABYT = BM * BK * 2;
  constexpr int BBYT = 128 * BK * 2;
  constexpr int APW = BM / 32;
  constexpr int IFL = APW + 4;
  constexpr int WM = BM / 2, MT = WM / 16;
  __shared__ alignas(16) char smem[2 * ABYT + 2 * BBYT];

  const int tid = threadIdx.x, lane = tid & 63, wid = tid >> 6;
  const int wrow = wid >> 1, wcol = wid & 1;
  const int m0 = blockIdx.x * BM, n0 = blockIdx.y * 128;
  const int l8 = lane & 7, ld8 = lane >> 3;
  const int swz = (l8 ^ ld8) * 8;

  const __hip_bfloat16* Abase = A + (size_t)m0 * K;
  const __hip_bfloat16* Bbase = Bn + (size_t)n0 * K;

  f32x4 acc[MT][4];
#pragma unroll
  for (int i = 0; i < MT; ++i)
#pragma unroll
    for (int j = 0; j < 4; ++j) acc[i][j] = {0.f, 0.f, 0.f, 0.f};

  auto stage = [&](int buf, int kt) {
    const __hip_bfloat16* as = Abase + kt * BK + swz;
    char* ad = smem + buf * ABYT;
#pragma unroll
    for (int s = 0; s < APW; ++s) {
      int iss = wid * APW + s;
      async16(as + (size_t)(iss * 8 + ld8) * K, ad + iss * 1024);
    }
    const __hip_bfloat16* bs = Bbase + kt * BK + swz;
    char* bd = smem + 2 * ABYT + buf * BBYT;
#pragma unroll
    for (int s = 0; s < 4; ++s) {
      int iss = wid * 4 + s;
      async16(bs + (size_t)(iss * 8 + ld8) * K, bd + iss * 1024);
    }
  };

  const int nk = K / BK;
  stage(0, 0);
  for (int kt = 0; kt < nk; ++kt) {
    if (kt + 1 < nk) {
      stage((kt + 1) & 1, kt + 1);
      vmwait_barrier<IFL>();
    } else {
      vmwait_barrier<0>();
    }
    const __hip_bfloat16* ab = (const __hip_bfloat16*)(smem + (kt & 1) * ABYT);
    const __hip_bfloat16* bb = (const __hip_bfloat16*)(smem + 2 * ABYT + (kt & 1) * BBYT);
#pragma unroll
    for (int kk = 0; kk < BK; kk += 32) {
      bf16x8 af[MT], bf[4];
#pragma unroll
      for (int i = 0; i < MT; ++i) {
        int r = wrow * WM + i * 16 + (lane & 15);
        af[i] = *(const bf16x8*)&ab[r * BK + ((kk + (lane >> 4) * 8) ^ ((r & 7) * 8))];
      }
#pragma unroll
      for (int j = 0; j < 4; ++j) {
        int r = wcol * 64 + j * 16 + (lane & 15);
        bf[j] = *(const bf16x8*)&bb[r * BK + ((kk + (lane >> 4) * 8) ^ ((r & 7) * 8))];
      }
#pragma unroll
      for (int i = 0; i < MT; ++i)
#pragma unroll
        for (int j = 0; j < 4; ++j)
          acc[i][j] = __builtin_amdgcn_mfma_f32_16x16x32_bf16(af[i], bf[j], acc[i][j], 0, 0, 0);
    }
    __builtin_amdgcn_s_barrier();
  }
  __syncthreads();

  // LDS bounce: swz=(row&7)<<2 -> 2-way writes (free), bank-balanced reads.
  float* Csm = (float*)smem;
#pragma unroll
  for (int i = 0; i < MT; ++i)
#pragma unroll
    for (int j = 0; j < 4; ++j)
#pragma unroll
      for (int rr = 0; rr < 4; ++rr) {
        int row = wrow * WM + i * 16 + (lane >> 4) * 4 + rr;
        int col = wcol * 64 + j * 16 + (lane & 15);
        Csm[row * 128 + (col ^ ((row & 7) << 2))] = acc[i][j][rr];
      }
  __syncthreads();
#pragma unroll
  for (int it = 0; it < BM / 16; ++it) {
    int idx = it * 256 + tid;
    int row = idx >> 4;
    int cb = (idx & 15) * 8;
    int sw = (row & 7) << 2;
    float4 v0 = *(const float4*)&Csm[row * 128 + (cb ^ sw)];
    float4 v1 = *(const float4*)&Csm[row * 128 + ((cb + 4) ^ sw)];
    float4 b0 = *(const float4*)&bias[n0 + cb];
    float4 b1 = *(const float4*)&bias[n0 + cb + 4];
    v0.x += b0.x; v0.y += b0.y; v0.z += b0.z; v0.w += b0.w;
    v1.x += b1.x; v1.y += b1.y; v1.z += b1.z; v1.w += b1.w;
    size_t base = (size_t)(m0 + row) * ldc + n0 + cb;
    if (EPI == 0) {
      union { __hip_bfloat16 h[8]; uint4 u; } o;
      o.h[0] = f2b(v0.x); o.h[1] = f2b(v0.y); o.h[2] = f2b(v0.z); o.h[3] = f2b(v0.w);
      o.h[4] = f2b(v1.x); o.h[5] = f2b(v1.y); o.h[6] = f2b(v1.z); o.h[7] = f2b(v1.w);
      *(uint4*)&((__hip_bfloat16*)Cout)[base] = o.u;
    } else {
      v0.x = fmaxf(v0.x, 0.f); v0.y = fmaxf(v0.y, 0.f);
      v0.z = fmaxf(v0.z, 0.f); v0.w = fmaxf(v0.w, 0.f);
      v1.x = fmaxf(v1.x, 0.f); v1.y = fmaxf(v1.y, 0.f);
      v1.z = fmaxf(v1.z, 0.f); v1.w = fmaxf(v1.w, 0.f);
      *(float4*)&((float*)Cout)[base] = v0;
      *(float4*)&((float*)Cout)[base + 4] = v1;
    }
  }
}

// ---------------------------------------------------------------------------
// Persistent recurrence: grid (16 mt x 16 jt) = 256 wgs, 1/CU (forced by 96KB
// dynamic LDS). Wave-owned W_hh fragments in VGPRs (loaded once via LDS bounce),
// c-state in VGPRs, h ping-pong in global, mt-group (16 wg) barriers per step.
// LDS: [0,64K) A-chunks (8 x 8KB) / gsm f32 alias; [64K,80K) xsm.
__global__ __launch_bounds__(256, 1)
void lstm_persist(const __hip_bfloat16* __restrict__ xp,
                  const __hip_bfloat16* __restrict__ Whh,
                  __hip_bfloat16* __restrict__ hA,
                  __hip_bfloat16* __restrict__ hB,
                  int* __restrict__ ctr) {
  extern __shared__ char smem[];
  const int tid = threadIdx.x, lane = tid & 63, wid = tid >> 6;
  const int mt = blockIdx.x, jt = blockIdx.y;
  const int m0 = mt * 64;
  const int l8 = lane & 7, ld8 = lane >> 3;
  const int swz = (l8 ^ ld8) * 8;

  // ---- one-time: W slice (128 gate-rows x 512 K) -> 32 B-frags in VGPRs ----
  bf16x8 w[2][16];
  for (int h = 0; h < 2; ++h) {
#pragma unroll
    for (int kt = 0; kt < 8; ++kt)
#pragma unroll
      for (int s = 0; s < 2; ++s) {
        int iss = wid * 2 + s;
        int r = h * 64 + iss * 8 + ld8;               // global tile gate-row
        int g = jt * 32 + (r >> 5) * 512 + (r & 31);  // gate-chunk i,f,g,o
        async16(Whh + (size_t)g * 512 + kt * 64 + swz,
                smem + kt * 8192 + iss * 1024);
      }
    asm volatile("s_waitcnt vmcnt(0)" ::: "memory");
    __builtin_amdgcn_s_barrier();
    __builtin_amdgcn_sched_barrier(0);
    if ((wid >> 1) == h) {
      const __hip_bfloat16* wb = (const __hip_bfloat16*)smem;
      const int lw = wid & 1;
#pragma unroll
      for (int j = 0; j < 2; ++j)
#pragma unroll
        for (int ka = 0; ka < 16; ++ka) {
          int r = lw * 32 + j * 16 + (lane & 15);  // local row in half
          int kt = ka >> 1, kk = (ka & 1) * 32;
          w[j][ka] = *(const bf16x8*)&wb[kt * 4096 + r * 64 +
                                         ((kk + (lane >> 4) * 8) ^ ((r & 7) * 8))];
        }
    }
    __syncthreads();
  }

  float c_[8];
#pragma unroll
  for (int e = 0; e < 8; ++e) c_[e] = 0.f;

  const int pr = tid >> 2, pj = (tid & 3) * 8;  // pointwise ownership (fixed)

  for (int t = 0; t < 64; ++t) {
    const __hip_bfloat16* hin = (t & 1) ? hB : hA;
    __hip_bfloat16* hout = (t & 1) ? hA : hB;

    // A stage: 8 chunks x 2 issues/thread (order matters for vmcnt counting)
#pragma unroll
    for (int kt = 0; kt < 8; ++kt)
#pragma unroll
      for (int s = 0; s < 2; ++s) {
        int iss = wid * 2 + s;
        async16(hin + (size_t)(m0 + iss * 8 + ld8) * 512 + kt * 64 + swz,
                smem + kt * 8192 + iss * 1024);
      }
    // xp prefetch (4 issues; consumed in pointwise, latency fully hidden)
    {
      const int rowbase = (mt < 8) ? (t * 512 + m0) : ((63 - t) * 512 + (m0 - 512));
#pragma unroll
      for (int s = 0; s < 4; ++s) {
        int iss = wid * 4 + s;
        const __hip_bfloat16* src = xp + (size_t)(rowbase + iss * 4 + (lane >> 4)) * 2048 +
                                    ((lane >> 2) & 3) * 512 + jt * 32 + (lane & 3) * 8;
        async16(src, smem + 65536 + iss * 1024);
      }
    }

    f32x4 acc[4][2];
#pragma unroll
    for (int i = 0; i < 4; ++i)
#pragma unroll
      for (int j = 0; j < 2; ++j) acc[i][j] = {0.f, 0.f, 0.f, 0.f};

    auto do_kt = [&](auto K) {
      constexpr int KT = decltype(K)::v;
      vmwait_barrier<18 - 2 * KT>();  // 2(KT+1) A-issues done; xp may float
      const __hip_bfloat16* ab = (const __hip_bfloat16*)(smem + KT * 8192);
#pragma unroll
      for (int kk = 0; kk < 64; kk += 32) {
        bf16x8 af[4];
#pragma unroll
        for (int i = 0; i < 4; ++i) {
          int r = i * 16 + (lane & 15);
          af[i] = *(const bf16x8*)&ab[r * 64 + ((kk + (lane >> 4) * 8) ^ ((r & 7) * 8))];
        }
#pragma unroll
        for (int i = 0; i < 4; ++i)
#pragma unroll
          for (int j = 0; j < 2; ++j)
            acc[i][j] = __builtin_amdgcn_mfma_f32_16x16x32_bf16(
                af[i], w[j][KT * 2 + kk / 32], acc[i][j], 0, 0, 0);
      }
    };
    do_kt(IC<0>{}); do_kt(IC<1>{}); do_kt(IC<2>{}); do_kt(IC<3>{});
    do_kt(IC<4>{}); do_kt(IC<5>{}); do_kt(IC<6>{}); do_kt(IC<7>{});

    __syncthreads();  // A reads done -> gsm may alias [0,32K)
    float* gsm = (float*)smem;
#pragma unroll
    for (int i = 0; i < 4; ++i)
#pragma unroll
      for (int j = 0; j < 2; ++j)
#pragma unroll
        for (int rr = 0; rr < 4; ++rr) {
          int row = i * 16 + (lane >> 4) * 4 + rr;
          int col = wid * 32 + j * 16 + (lane & 15);
          gsm[row * 128 + col] = acc[i][j][rr];
        }
    __syncthreads();
    asm volatile("s_waitcnt vmcnt(0)" ::: "memory");  // xsm landed

    // fused pointwise: thread owns (row pr, cols pj..pj+7); c in regs
    const __hip_bfloat16* xsm = (const __hip_bfloat16*)(smem + 65536);
    bf16x8 xi = *(const bf16x8*)&xsm[(pr * 4 + 0) * 32 + pj];
    bf16x8 xf = *(const bf16x8*)&xsm[(pr * 4 + 1) * 32 + pj];
    bf16x8 xg = *(const bf16x8*)&xsm[(pr * 4 + 2) * 32 + pj];
    bf16x8 xo = *(const bf16x8*)&xsm[(pr * 4 + 3) * 32 + pj];
    union { __hip_bfloat16 h[8]; uint4 u; } ho;
#pragma unroll
    for (int e = 0; e < 8; ++e) {
      float gi = gsm[pr * 128 + pj + e]      + b2f(((__hip_bfloat16*)&xi)[e]);
      float gf = gsm[pr * 128 + 32 + pj + e] + b2f(((__hip_bfloat16*)&xf)[e]);
      float gg = gsm[pr * 128 + 64 + pj + e] + b2f(((__hip_bfloat16*)&xg)[e]);
      float go = gsm[pr * 128 + 96 + pj + e] + b2f(((__hip_bfloat16*)&xo)[e]);
      float cn = sigmf_(gf) * c_[e] + sigmf_(gi) * tanhf_(gg);
      float hn = sigmf_(go) * tanhf_(cn);
      c_[e] = cn;
      ho.h[e] = f2b(hn);
    }
    *(uint4*)&hout[(size_t)(m0 + pr) * 512 + jt * 32 + pj] = ho.u;

    // mt-group barrier (16 wgs share rows m0..m0+63)
    asm volatile("s_waitcnt vmcnt(0) lgkmcnt(0)" ::: "memory");
    __syncthreads();
    if (t < 63) {
      if (tid == 0) {
        __threadfence();                       // release (L2 writeback)
        atomicAdd(&ctr[mt * 64], 1);
        const int target = 16 * (t + 1);
        while (__hip_atomic_load(&ctr[mt * 64], __ATOMIC_RELAXED,
                                 __HIP_MEMORY_SCOPE_AGENT) < target)
          __builtin_amdgcn_s_sleep(1);
        __threadfence();                       // acquire (invalidate L1/L2)
      }
      __syncthreads();
    }
  }
}

// ---------------------------------------------------------------------------
__global__ void feat_kernel(const __hip_bfloat16* __restrict__ hA, float* __restrict__ feat) {
  int b = blockIdx.x;
  for (int c = threadIdx.x; c < 2048; c += 256) {
    int sec = c >> 9, j = c & 511;
    int row = (sec == 0) ? b : (sec == 1) ? 512 + b : (sec == 2) ? 256 + b : 768 + b;
    feat[b * 2048 + c] = b2f(hA[(size_t)row * 512 + j]);
  }
}

__global__ void bn_stats(const float* __restrict__ x, const float* __restrict__ g,
                         const float* __restrict__ b,
                         float* __restrict__ sc, float* __restrict__ sh) {
  int c = blockIdx.x * 256 + threadIdx.x;
  float s = 0.f, s2 = 0.f;
  for (int r = 0; r < 256; ++r) {
    float v = x[r * 2048 + c];
    s += v;
    s2 += v * v;
  }
  float mu = s * (1.f / 256.f);
  float var = s2 * (1.f / 256.f) - mu * mu;
  float rs = rsqrtf(var + 1e-5f);
  float scale = g[c] * rs;
  sc[c] = scale;
  sh[c] = b[c] - mu * scale;
}

__global__ void bn_apply(const float* __restrict__ x, const float* __restrict__ sc,
                         const float* __restrict__ sh, __hip_bfloat16* __restrict__ xn) {
  int i = blockIdx.x * 256 + threadIdx.x;
  int c = i & 2047;
  xn[i] = f2b(x[i] * sc[c] + sh[c]);
}

__global__ void final_kernel(const float* __restrict__ x2, const float* __restrict__ sc,
                             const float* __restrict__ sh, const float* __restrict__ Wo,
                             const float* __restrict__ bo, float* __restrict__ out) {
  __shared__ float red[3][256];
  int b = blockIdx.x, tid = threadIdx.x;
  float a0 = 0.f, a1 = 0.f, a2 = 0.f;
  for (int c = tid; c < 2048; c += 256) {
    float v = x2[b * 2048 + c] * sc[c] + sh[c];
    a0 += v * Wo[c];
    a1 += v * Wo[2048 + c];
    a2 += v * Wo[4096 + c];
  }
  red[0][tid] = a0; red[1][tid] = a1; red[2][tid] = a2;
  __syncthreads();
  for (int s = 128; s > 0; s >>= 1) {
    if (tid < s) {
      red[0][tid] += red[0][tid + s];
      red[1][tid] += red[1][tid + s];
      red[2][tid] += red[2][tid + s];
    }
    __syncthreads();
  }
  if (tid < 3) out[b * 3 + tid] = red[tid][0] + bo[tid];
}

// ---------------------------------------------------------------------------
extern "C" void kernel_launch(void* const* d_in, const int* in_sizes, int n_in,
                              void* d_out, int out_size, void* d_ws, size_t ws_size,
                              hipStream_t stream) {
  (void)in_sizes; (void)n_in; (void)out_size; (void)ws_size;
  const int* prem = (const int*)d_in[0];
  const int* hyp = (const int*)d_in[1];
  const float* embed = (const float*)d_in[2];
  const float* W_ih = (const float*)d_in[3];
  const float* W_hh = (const float*)d_in[4];
  const float* b_ih = (const float*)d_in[5];
  const float* b_hh = (const float*)d_in[6];
  const float* bn0g = (const float*)d_in[7];
  const float* bn0b = (const float*)d_in[8];
  const float* W0 = (const float*)d_in[9];
  const float* b0 = (const float*)d_in[10];
  const float* bn1g = (const float*)d_in[11];
  const float* bn1b = (const float*)d_in[12];
  const float* W1 = (const float*)d_in[13];
  const float* b1 = (const float*)d_in[14];
  const float* bnog = (const float*)d_in[15];
  const float* bnob = (const float*)d_in[16];
  const float* Wo = (const float*)d_in[17];
  const float* bo = (const float*)d_in[18];
  float* out = (float*)d_out;

  char* w = (char*)d_ws;
  size_t off = 0;
  auto alloc = [&](size_t bytes) {
    void* p = w + off;
    off += (bytes + 255) & ~(size_t)255;
    return p;
  };
  __hip_bfloat16* WihP = (__hip_bfloat16*)alloc((size_t)2048 * 320 * 2);
  __hip_bfloat16* Whhb = (__hip_bfloat16*)alloc((size_t)2048 * 512 * 2);
  __hip_bfloat16* W0b = (__hip_bfloat16*)alloc((size_t)2048 * 2048 * 2);
  __hip_bfloat16* W1b = (__hip_bfloat16*)alloc((size_t)2048 * 2048 * 2);
  float* biasL = (float*)alloc(2048 * 4);
  int* ctr = (int*)alloc(16 * 64 * 4);  // mt-group barrier counters (padded)
  __hip_bfloat16* xp = (__hip_bfloat16*)alloc((size_t)32768 * 2048 * 2);  // 128 MiB
  size_t ain_off = off;
  __hip_bfloat16* Ain = (__hip_bfloat16*)alloc((size_t)32768 * 320 * 2);  // 20 MiB
  size_t end_off = off;
  off = ain_off;  // post-GEMM block aliases Ain (dead after xproj)
  __hip_bfloat16* hA = (__hip_bfloat16*)alloc((size_t)1024 * 512 * 2);
  __hip_bfloat16* hB = (__hip_bfloat16*)alloc((size_t)1024 * 512 * 2);
  float* feat = (float*)alloc((size_t)256 * 2048 * 4);
  __hip_bfloat16* xn = (__hip_bfloat16*)alloc((size_t)256 * 2048 * 2);
  float* x1 = (float*)alloc((size_t)256 * 2048 * 4);
  float* x2 = (float*)alloc((size_t)256 * 2048 * 4);
  float* sc0 = (float*)alloc(2048 * 4);
  float* sh0 = (float*)alloc(2048 * 4);
  float* sc1 = (float*)alloc(2048 * 4);
  float* sh1 = (float*)alloc(2048 * 4);
  float* sc2 = (float*)alloc(2048 * 4);
  float* sh2 = (float*)alloc(2048 * 4);
  (void)end_off;

  hipMemsetAsync(ctr, 0, 16 * 64 * 4, stream);  // fresh barrier state EVERY launch
  pack_wih<<<512, 256, 0, stream>>>(W_ih, b_ih, b_hh, WihP, biasL);
  cvt_f32_bf16<<<1024, 256, 0, stream>>>(W_hh, Whhb, 2048 * 512 / 4);
  cvt_f32_bf16<<<2048, 256, 0, stream>>>(W0, W0b, 2048 * 2048 / 4);
  cvt_f32_bf16<<<2048, 256, 0, stream>>>(W1, W1b, 2048 * 2048 / 4);
  gather_kernel<<<8192, 256, 0, stream>>>(prem, hyp, embed, Ain);
  // x_proj = combined @ W_ih^T + (b_ih + b_hh) : M=32768, N=2048, K=320
  gemm_pipe<128, 0><<<dim3(256, 16), 256, 0, stream>>>(Ain, WihP, biasL, xp, 320, 2048);
  hipMemsetAsync(hA, 0, (size_t)1024 * 512 * 2, stream);  // h0 = 0 (aliases Ain)
  // persistent recurrence: 96KB dyn LDS forces 1 wg/CU -> all 256 co-resident
  hipFuncSetAttribute(reinterpret_cast<const void*>(lstm_persist),
                      hipFuncAttributeMaxDynamicSharedMemorySize, 98304);
  lstm_persist<<<dim3(16, 16), 256, 98304, stream>>>(xp, Whhb, hA, hB, ctr);
  feat_kernel<<<256, 256, 0, stream>>>(hA, feat);  // t=63 wrote hA
  bn_stats<<<8, 256, 0, stream>>>(feat, bn0g, bn0b, sc0, sh0);
  bn_apply<<<2048, 256, 0, stream>>>(feat, sc0, sh0, xn);
  gemm_pipe<64, 1><<<dim3(4, 16), 256, 0, stream>>>(xn, W0b, b0, x1, 2048, 2048);
  bn_stats<<<8, 256, 0, stream>>>(x1, bn1g, bn1b, sc1, sh1);
  bn_apply<<<2048, 256, 0, stream>>>(x1, sc1, sh1, xn);
  gemm_pipe<64, 1><<<dim3(4, 16), 256, 0, stream>>>(xn, W1b, b1, x2, 2048, 2048);
  bn_stats<<<8, 256, 0, stream>>>(x2, bnog, bnob, sc2, sh2);
  final_kernel<<<256, 256, 0, stream>>>(x2, sc2, sh2, Wo, bo, out);
}

// Round 6
// 490.321 us; speedup vs baseline: 2.0637x; 2.0637x over previous
//
#include <hip/hip_runtime.h>
#include <hip/hip_bf16.h>

// ConcatModel (all I/O f32; internal MFMA compute bf16, f32 accumulate):
// embed-gather(cvt) -> input-proj GEMM (pipelined) -> ONE persistent LSTM
// recurrence kernel (W_hh in AGPRs, c in VGPRs, L3-coherent h exchange via
// sc0/sc1, NO L2 writeback fences) -> feat -> (BN -> GEMM+ReLU) x2 -> BN -> out.

typedef __attribute__((ext_vector_type(8))) short bf16x8;
typedef __attribute__((ext_vector_type(4))) float f32x4;
typedef __attribute__((ext_vector_type(4))) unsigned int u32x4;

#define DEVI __device__ __forceinline__

template<int N> struct IC { static constexpr int v = N; };

DEVI void async16(const void* g, void* l) {
  __builtin_amdgcn_global_load_lds((const __attribute__((address_space(1))) void*)g,
                                   (__attribute__((address_space(3))) void*)l,
                                   16, 0, 0);
}
// device-coherent (sc0|sc1 = 1|16): bypass stale L1/L2, read at L3 coherence point
DEVI void async16_coh(const void* g, void* l) {
  __builtin_amdgcn_global_load_lds((const __attribute__((address_space(1))) void*)g,
                                   (__attribute__((address_space(3))) void*)l,
                                   16, 0, 17);
}
// device-coherent 16B store: write-through (visible to all XCDs once vmcnt retires)
DEVI void store16_coh(void* addr, u32x4 v) {
  asm volatile("global_store_dwordx4 %0, %1, off sc0 sc1" ::"v"(addr), "v"(v) : "memory");
}
template<int N> DEVI void vmwait_barrier() {
  asm volatile("s_waitcnt vmcnt(%0)" ::"i"(N) : "memory");
  __builtin_amdgcn_s_barrier();
  __builtin_amdgcn_sched_barrier(0);
}
DEVI float sigmf_(float x) { return 1.f / (1.f + __expf(-x)); }
DEVI float tanhf_(float x) {
  float a = __expf(-2.f * fabsf(x));
  float t = (1.f - a) / (1.f + a);
  return copysignf(t, x);
}
DEVI __hip_bfloat16 f2b(float x) { return __float2bfloat16(x); }
DEVI float b2f(__hip_bfloat16 x) { return __bfloat162float(x); }

// ---------------------------------------------------------------------------
__global__ void cvt_f32_bf16(const float* __restrict__ src,
                             __hip_bfloat16* __restrict__ dst, int n4) {
  int i = blockIdx.x * 256 + threadIdx.x;
  int stride = gridDim.x * 256;
  for (; i < n4; i += stride) {
    float4 v = ((const float4*)src)[i];
    union { __hip_bfloat16 h[4]; uint2 u; } o;
    o.h[0] = f2b(v.x); o.h[1] = f2b(v.y); o.h[2] = f2b(v.z); o.h[3] = f2b(v.w);
    ((uint2*)dst)[i] = o.u;
  }
}

__global__ void pack_wih(const float* __restrict__ W_ih,
                         const float* __restrict__ b_ih,
                         const float* __restrict__ b_hh,
                         __hip_bfloat16* __restrict__ WihP,
                         float* __restrict__ biasL) {
  int tid = blockIdx.x * 256 + threadIdx.x;
  int stride = gridDim.x * 256;
  for (int i = tid; i < 2048 * 320; i += stride) {
    int r = i / 320, c = i - r * 320;
    WihP[i] = (c < 300) ? f2b(W_ih[r * 300 + c]) : f2b(0.f);
  }
  if (tid < 2048) biasL[tid] = b_ih[tid] + b_hh[tid];
}

// gather+cvt: Ain[m][0..319] bf16, m = t*512 + n; n<256 premise else hypothesis.
__global__ void gather_kernel(const int* __restrict__ prem, const int* __restrict__ hyp,
                              const float* __restrict__ embed,
                              __hip_bfloat16* __restrict__ Ain) {
  int row = blockIdx.x * 4 + (threadIdx.x >> 6);
  int lane = threadIdx.x & 63;
  int tt = row >> 9, n = row & 511;
  int tok = (n < 256) ? prem[tt * 256 + n] : hyp[tt * 256 + (n - 256)];
  const float4* e4 = (const float4*)(embed + (size_t)tok * 300);  // 75 x 16B
  uint2* d2 = (uint2*)(Ain + (size_t)row * 320);                  // 80 x 8B
  for (int j = lane; j < 75; j += 64) {
    float4 v = e4[j];
    union { __hip_bfloat16 h[4]; uint2 u; } o;
    o.h[0] = f2b(v.x); o.h[1] = f2b(v.y); o.h[2] = f2b(v.z); o.h[3] = f2b(v.w);
    d2[j] = o.u;
  }
  for (int j = 75 + lane; j < 80; j += 64) d2[j] = make_uint2(0u, 0u);
}

// ---------------------------------------------------------------------------
// Pipelined GEMM: C[M][N=128/blk] = A[M][K] * Bn[N][K]^T (+bias).
template<int BM, int EPI>
__global__ __launch_bounds__(256)
void gemm_pipe(const __hip_bfloat16* __restrict__ A,
               const __hip_bfloat16* __restrict__ Bn,
               const float* __restrict__ bias,
               void* __restrict__ Cout, int K, int ldc) {
  constexpr int BK = 64;
  constexpr int ABYT = BM * BK * 2;
  constexpr int BBYT = 128 * BK * 2;
  constexpr int APW = BM / 32;
  constexpr int IFL = APW + 4;
  constexpr int WM = BM / 2, MT = WM / 16;
  __shared__ alignas(16) char smem[2 * ABYT + 2 * BBYT];

  const int tid = threadIdx.x, lane = tid & 63, wid = tid >> 6;
  const int wrow = wid >> 1, wcol = wid & 1;
  const int m0 = blockIdx.x * BM, n0 = blockIdx.y * 128;
  const int l8 = lane & 7, ld8 = lane >> 3;
  const int swz = (l8 ^ ld8) * 8;

  const __hip_bfloat16* Abase = A + (size_t)m0 * K;
  const __hip_bfloat16* Bbase = Bn + (size_t)n0 * K;

  f32x4 acc[MT][4];
#pragma unroll
  for (int i = 0; i < MT; ++i)
#pragma unroll
    for (int j = 0; j < 4; ++j) acc[i][j] = {0.f, 0.f, 0.f, 0.f};

  auto stage = [&](int buf, int kt) {
    const __hip_bfloat16* as = Abase + kt * BK + swz;
    char* ad = smem + buf * ABYT;
#pragma unroll
    for (int s = 0; s < APW; ++s) {
      int iss = wid * APW + s;
      async16(as + (size_t)(iss * 8 + ld8) * K, ad + iss * 1024);
    }
    const __hip_bfloat16* bs = Bbase + kt * BK + swz;
    char* bd = smem + 2 * ABYT + buf * BBYT;
#pragma unroll
    for (int s = 0; s < 4; ++s) {
      int iss = wid * 4 + s;
      async16(bs + (size_t)(iss * 8 + ld8) * K, bd + iss * 1024);
    }
  };

  const int nk = K / BK;
  stage(0, 0);
  for (int kt = 0; kt < nk; ++kt) {
    if (kt + 1 < nk) {
      stage((kt + 1) & 1, kt + 1);
      vmwait_barrier<IFL>();
    } else {
      vmwait_barrier<0>();
    }
    const __hip_bfloat16* ab = (const __hip_bfloat16*)(smem + (kt & 1) * ABYT);
    const __hip_bfloat16* bb = (const __hip_bfloat16*)(smem + 2 * ABYT + (kt & 1) * BBYT);
#pragma unroll
    for (int kk = 0; kk < BK; kk += 32) {
      bf16x8 af[MT], bf[4];
#pragma unroll
      for (int i = 0; i < MT; ++i) {
        int r = wrow * WM + i * 16 + (lane & 15);
        af[i] = *(const bf16x8*)&ab[r * BK + ((kk + (lane >> 4) * 8) ^ ((r & 7) * 8))];
      }
#pragma unroll
      for (int j = 0; j < 4; ++j) {
        int r = wcol * 64 + j * 16 + (lane & 15);
        bf[j] = *(const bf16x8*)&bb[r * BK + ((kk + (lane >> 4) * 8) ^ ((r & 7) * 8))];
      }
#pragma unroll
      for (int i = 0; i < MT; ++i)
#pragma unroll
        for (int j = 0; j < 4; ++j)
          acc[i][j] = __builtin_amdgcn_mfma_f32_16x16x32_bf16(af[i], bf[j], acc[i][j], 0, 0, 0);
    }
    __builtin_amdgcn_s_barrier();
  }
  __syncthreads();

  float* Csm = (float*)smem;
#pragma unroll
  for (int i = 0; i < MT; ++i)
#pragma unroll
    for (int j = 0; j < 4; ++j)
#pragma unroll
      for (int rr = 0; rr < 4; ++rr) {
        int row = wrow * WM + i * 16 + (lane >> 4) * 4 + rr;
        int col = wcol * 64 + j * 16 + (lane & 15);
        Csm[row * 128 + (col ^ ((row & 7) << 2))] = acc[i][j][rr];
      }
  __syncthreads();
#pragma unroll
  for (int it = 0; it < BM / 16; ++it) {
    int idx = it * 256 + tid;
    int row = idx >> 4;
    int cb = (idx & 15) * 8;
    int sw = (row & 7) << 2;
    float4 v0 = *(const float4*)&Csm[row * 128 + (cb ^ sw)];
    float4 v1 = *(const float4*)&Csm[row * 128 + ((cb + 4) ^ sw)];
    float4 b0 = *(const float4*)&bias[n0 + cb];
    float4 b1 = *(const float4*)&bias[n0 + cb + 4];
    v0.x += b0.x; v0.y += b0.y; v0.z += b0.z; v0.w += b0.w;
    v1.x += b1.x; v1.y += b1.y; v1.z += b1.z; v1.w += b1.w;
    size_t base = (size_t)(m0 + row) * ldc + n0 + cb;
    if (EPI == 0) {
      union { __hip_bfloat16 h[8]; uint4 u; } o;
      o.h[0] = f2b(v0.x); o.h[1] = f2b(v0.y); o.h[2] = f2b(v0.z); o.h[3] = f2b(v0.w);
      o.h[4] = f2b(v1.x); o.h[5] = f2b(v1.y); o.h[6] = f2b(v1.z); o.h[7] = f2b(v1.w);
      *(uint4*)&((__hip_bfloat16*)Cout)[base] = o.u;
    } else {
      v0.x = fmaxf(v0.x, 0.f); v0.y = fmaxf(v0.y, 0.f);
      v0.z = fmaxf(v0.z, 0.f); v0.w = fmaxf(v0.w, 0.f);
      v1.x = fmaxf(v1.x, 0.f); v1.y = fmaxf(v1.y, 0.f);
      v1.z = fmaxf(v1.z, 0.f); v1.w = fmaxf(v1.w, 0.f);
      *(float4*)&((float*)Cout)[base] = v0;
      *(float4*)&((float*)Cout)[base + 4] = v1;
    }
  }
}

// ---------------------------------------------------------------------------
// Persistent recurrence: 256 wgs (all co-resident), wg = (mt-group grp, jt).
// W_hh slice in AGPRs, c in VGPRs. Per-step h exchange THROUGH the coherence
// point (sc0|sc1 stores + aux=17 loads) + one device atomic per wg; no
// wbl2/inv fences -> L2 stays hot for xp.
// LDS: [0,64K) A k-tiles (8x8KB) / gsm f32[64][129] alias; [64K,80K) xsm.
__global__ __launch_bounds__(256, 1)
void lstm_persist(const __hip_bfloat16* __restrict__ xp,
                  const __hip_bfloat16* __restrict__ Whh,
                  __hip_bfloat16* __restrict__ hA,
                  __hip_bfloat16* __restrict__ hB,
                  int* __restrict__ ctr) {
  extern __shared__ char smem[];
  const int tid = threadIdx.x, lane = tid & 63, wid = tid >> 6;
  const int bid = blockIdx.x;
  const int grp = (bid & 7) | ((bid >> 7) << 3);  // 16 wgs of grp on same XCD (heuristic)
  const int jt = (bid >> 3) & 15;
  const int m0 = grp * 64;
  const int l8 = lane & 7, ld8 = lane >> 3;
  const int swz = (l8 ^ ld8) * 8;

  // ---- one-time: W slice (128 gate-rows x 512 K) -> 32 B-frags (AGPR file) ----
  bf16x8 w[2][16];
  for (int h = 0; h < 2; ++h) {
#pragma unroll
    for (int kt = 0; kt < 8; ++kt)
#pragma unroll
      for (int s = 0; s < 2; ++s) {
        int iss = wid * 2 + s;
        int r = h * 64 + iss * 8 + ld8;
        int g = jt * 32 + (r >> 5) * 512 + (r & 31);  // gate-chunk i,f,g,o
        async16(Whh + (size_t)g * 512 + kt * 64 + swz,
                smem + kt * 8192 + iss * 1024);
      }
    asm volatile("s_waitcnt vmcnt(0)" ::: "memory");
    __builtin_amdgcn_s_barrier();
    __builtin_amdgcn_sched_barrier(0);
    if ((wid >> 1) == h) {
      const __hip_bfloat16* wb = (const __hip_bfloat16*)smem;
      const int lw = wid & 1;
#pragma unroll
      for (int j = 0; j < 2; ++j)
#pragma unroll
        for (int ka = 0; ka < 16; ++ka) {
          int r = lw * 32 + j * 16 + (lane & 15);
          int kt = ka >> 1, kk = (ka & 1) * 32;
          w[j][ka] = *(const bf16x8*)&wb[kt * 4096 + r * 64 +
                                         ((kk + (lane >> 4) * 8) ^ ((r & 7) * 8))];
        }
    }
    __syncthreads();
  }

  float c_[8];
#pragma unroll
  for (int e = 0; e < 8; ++e) c_[e] = 0.f;

  const int pr = tid >> 2, pj = (tid & 3) * 8;  // pointwise ownership (fixed)

  for (int t = 0; t < 64; ++t) {
    const __hip_bfloat16* hin = (t & 1) ? hB : hA;
    __hip_bfloat16* hout = (t & 1) ? hA : hB;

    // A stage (kt-major order for vmcnt counting), device-coherent reads
#pragma unroll
    for (int kt = 0; kt < 8; ++kt)
#pragma unroll
      for (int s = 0; s < 2; ++s) {
        int iss = wid * 2 + s;
        async16_coh(hin + (size_t)(m0 + iss * 8 + ld8) * 512 + kt * 64 + swz,
                    smem + kt * 8192 + iss * 1024);
      }
    // xp prefetch (normal cached path; read-only data)
    {
      const int rowbase = (grp < 8) ? (t * 512 + m0) : ((63 - t) * 512 + (m0 - 512));
#pragma unroll
      for (int s = 0; s < 4; ++s) {
        int iss = wid * 4 + s;
        const __hip_bfloat16* src = xp + (size_t)(rowbase + iss * 4 + (lane >> 4)) * 2048 +
                                    ((lane >> 2) & 3) * 512 + jt * 32 + (lane & 3) * 8;
        async16(src, smem + 65536 + iss * 1024);
      }
    }

    f32x4 acc[4][2];
#pragma unroll
    for (int i = 0; i < 4; ++i)
#pragma unroll
      for (int j = 0; j < 2; ++j) acc[i][j] = {0.f, 0.f, 0.f, 0.f};

    auto do_kt = [&](auto K) {
      constexpr int KT = decltype(K)::v;
      vmwait_barrier<18 - 2 * KT>();  // A-issues through kt retired; xp floats
      const __hip_bfloat16* ab = (const __hip_bfloat16*)(smem + KT * 8192);
#pragma unroll
      for (int kk = 0; kk < 64; kk += 32) {
        bf16x8 af[4];
#pragma unroll
        for (int i = 0; i < 4; ++i) {
          int r = i * 16 + (lane & 15);
          af[i] = *(const bf16x8*)&ab[r * 64 + ((kk + (lane >> 4) * 8) ^ ((r & 7) * 8))];
        }
#pragma unroll
        for (int i = 0; i < 4; ++i)
#pragma unroll
          for (int j = 0; j < 2; ++j)
            acc[i][j] = __builtin_amdgcn_mfma_f32_16x16x32_bf16(
                af[i], w[j][KT * 2 + kk / 32], acc[i][j], 0, 0, 0);
      }
    };
    do_kt(IC<0>{}); do_kt(IC<1>{}); do_kt(IC<2>{}); do_kt(IC<3>{});
    do_kt(IC<4>{}); do_kt(IC<5>{}); do_kt(IC<6>{}); do_kt(IC<7>{});

    __syncthreads();  // A reads done -> gsm may alias A region
    float* gsm = (float*)smem;  // stride 129: write 2-way, read ~2-way (free)
#pragma unroll
    for (int i = 0; i < 4; ++i)
#pragma unroll
      for (int j = 0; j < 2; ++j)
#pragma unroll
        for (int rr = 0; rr < 4; ++rr) {
          int row = i * 16 + (lane >> 4) * 4 + rr;
          int col = wid * 32 + j * 16 + (lane & 15);
          gsm[row * 129 + col] = acc[i][j][rr];
        }
    __syncthreads();
    asm volatile("s_waitcnt vmcnt(0)" ::: "memory");  // xsm landed

    const __hip_bfloat16* xsm = (const __hip_bfloat16*)(smem + 65536);
    bf16x8 xi = *(const bf16x8*)&xsm[(pr * 4 + 0) * 32 + pj];
    bf16x8 xf = *(const bf16x8*)&xsm[(pr * 4 + 1) * 32 + pj];
    bf16x8 xg = *(const bf16x8*)&xsm[(pr * 4 + 2) * 32 + pj];
    bf16x8 xo = *(const bf16x8*)&xsm[(pr * 4 + 3) * 32 + pj];
    union { __hip_bfloat16 h[8]; u32x4 u; } ho;
#pragma unroll
    for (int e = 0; e < 8; ++e) {
      float gi = gsm[pr * 129 + pj + e]      + b2f(((__hip_bfloat16*)&xi)[e]);
      float gf = gsm[pr * 129 + 32 + pj + e] + b2f(((__hip_bfloat16*)&xf)[e]);
      float gg = gsm[pr * 129 + 64 + pj + e] + b2f(((__hip_bfloat16*)&xg)[e]);
      float go = gsm[pr * 129 + 96 + pj + e] + b2f(((__hip_bfloat16*)&xo)[e]);
      float cn = sigmf_(gf) * c_[e] + sigmf_(gi) * tanhf_(gg);
      float hn = sigmf_(go) * tanhf_(cn);
      c_[e] = cn;
      ho.h[e] = f2b(hn);
    }
    // h write-through (device-visible once vmcnt retires)
    store16_coh(&hout[(size_t)(m0 + pr) * 512 + jt * 32 + pj], ho.u);
    asm volatile("s_waitcnt vmcnt(0)" ::: "memory");  // own store acked
    __syncthreads();                                   // whole wg's stores acked

    if (t < 63) {
      if (tid == 0) {
        atomicAdd(&ctr[grp * 64], 1);  // device-scope arrival
        const int target = 16 * (t + 1);
        while (__hip_atomic_load(&ctr[grp * 64], __ATOMIC_RELAXED,
                                 __HIP_MEMORY_SCOPE_AGENT) < target)
          __builtin_amdgcn_s_sleep(1);
      }
      __syncthreads();
    }
  }
}

// ---------------------------------------------------------------------------
__global__ void feat_kernel(const __hip_bfloat16* __restrict__ hA, float* __restrict__ feat) {
  int b = blockIdx.x;
  for (int c = threadIdx.x; c < 2048; c += 256) {
    int sec = c >> 9, j = c & 511;
    int row = (sec == 0) ? b : (sec == 1) ? 512 + b : (sec == 2) ? 256 + b : 768 + b;
    feat[b * 2048 + c] = b2f(hA[(size_t)row * 512 + j]);
  }
}

__global__ void bn_stats(const float* __restrict__ x, const float* __restrict__ g,
                         const float* __restrict__ b,
                         float* __restrict__ sc, float* __restrict__ sh) {
  int c = blockIdx.x * 256 + threadIdx.x;
  float s = 0.f, s2 = 0.f;
  for (int r = 0; r < 256; ++r) {
    float v = x[r * 2048 + c];
    s += v;
    s2 += v * v;
  }
  float mu = s * (1.f / 256.f);
  float var = s2 * (1.f / 256.f) - mu * mu;
  float rs = rsqrtf(var + 1e-5f);
  float scale = g[c] * rs;
  sc[c] = scale;
  sh[c] = b[c] - mu * scale;
}

__global__ void bn_apply(const float* __restrict__ x, const float* __restrict__ sc,
                         const float* __restrict__ sh, __hip_bfloat16* __restrict__ xn) {
  int i = blockIdx.x * 256 + threadIdx.x;
  int c = i & 2047;
  xn[i] = f2b(x[i] * sc[c] + sh[c]);
}

__global__ void final_kernel(const float* __restrict__ x2, const float* __restrict__ sc,
                             const float* __restrict__ sh, const float* __restrict__ Wo,
                             const float* __restrict__ bo, float* __restrict__ out) {
  __shared__ float red[3][256];
  int b = blockIdx.x, tid = threadIdx.x;
  float a0 = 0.f, a1 = 0.f, a2 = 0.f;
  for (int c = tid; c < 2048; c += 256) {
    float v = x2[b * 2048 + c] * sc[c] + sh[c];
    a0 += v * Wo[c];
    a1 += v * Wo[2048 + c];
    a2 += v * Wo[4096 + c];
  }
  red[0][tid] = a0; red[1][tid] = a1; red[2][tid] = a2;
  __syncthreads();
  for (int s = 128; s > 0; s >>= 1) {
    if (tid < s) {
      red[0][tid] += red[0][tid + s];
      red[1][tid] += red[1][tid + s];
      red[2][tid] += red[2][tid + s];
    }
    __syncthreads();
  }
  if (tid < 3) out[b * 3 + tid] = red[tid][0] + bo[tid];
}

// ---------------------------------------------------------------------------
extern "C" void kernel_launch(void* const* d_in, const int* in_sizes, int n_in,
                              void* d_out, int out_size, void* d_ws, size_t ws_size,
                              hipStream_t stream) {
  (void)in_sizes; (void)n_in; (void)out_size; (void)ws_size;
  const int* prem = (const int*)d_in[0];
  const int* hyp = (const int*)d_in[1];
  const float* embed = (const float*)d_in[2];
  const float* W_ih = (const float*)d_in[3];
  const float* W_hh = (const float*)d_in[4];
  const float* b_ih = (const float*)d_in[5];
  const float* b_hh = (const float*)d_in[6];
  const float* bn0g = (const float*)d_in[7];
  const float* bn0b = (const float*)d_in[8];
  const float* W0 = (const float*)d_in[9];
  const float* b0 = (const float*)d_in[10];
  const float* bn1g = (const float*)d_in[11];
  const float* bn1b = (const float*)d_in[12];
  const float* W1 = (const float*)d_in[13];
  const float* b1 = (const float*)d_in[14];
  const float* bnog = (const float*)d_in[15];
  const float* bnob = (const float*)d_in[16];
  const float* Wo = (const float*)d_in[17];
  const float* bo = (const float*)d_in[18];
  float* out = (float*)d_out;

  char* w = (char*)d_ws;
  size_t off = 0;
  auto alloc = [&](size_t bytes) {
    void* p = w + off;
    off += (bytes + 255) & ~(size_t)255;
    return p;
  };
  __hip_bfloat16* WihP = (__hip_bfloat16*)alloc((size_t)2048 * 320 * 2);
  __hip_bfloat16* Whhb = (__hip_bfloat16*)alloc((size_t)2048 * 512 * 2);
  __hip_bfloat16* W0b = (__hip_bfloat16*)alloc((size_t)2048 * 2048 * 2);
  __hip_bfloat16* W1b = (__hip_bfloat16*)alloc((size_t)2048 * 2048 * 2);
  float* biasL = (float*)alloc(2048 * 4);
  int* ctr = (int*)alloc(16 * 64 * 4);  // mt-group arrival counters (256B apart)
  __hip_bfloat16* xp = (__hip_bfloat16*)alloc((size_t)32768 * 2048 * 2);  // 128 MiB
  size_t ain_off = off;
  __hip_bfloat16* Ain = (__hip_bfloat16*)alloc((size_t)32768 * 320 * 2);  // 20 MiB
  size_t end_off = off;
  off = ain_off;  // post-GEMM block aliases Ain (dead after xproj)
  __hip_bfloat16* hA = (__hip_bfloat16*)alloc((size_t)1024 * 512 * 2);
  __hip_bfloat16* hB = (__hip_bfloat16*)alloc((size_t)1024 * 512 * 2);
  float* feat = (float*)alloc((size_t)256 * 2048 * 4);
  __hip_bfloat16* xn = (__hip_bfloat16*)alloc((size_t)256 * 2048 * 2);
  float* x1 = (float*)alloc((size_t)256 * 2048 * 4);
  float* x2 = (float*)alloc((size_t)256 * 2048 * 4);
  float* sc0 = (float*)alloc(2048 * 4);
  float* sh0 = (float*)alloc(2048 * 4);
  float* sc1 = (float*)alloc(2048 * 4);
  float* sh1 = (float*)alloc(2048 * 4);
  float* sc2 = (float*)alloc(2048 * 4);
  float* sh2 = (float*)alloc(2048 * 4);
  (void)end_off;

  (void)hipMemsetAsync(ctr, 0, 16 * 64 * 4, stream);  // fresh barrier state EVERY launch
  pack_wih<<<512, 256, 0, stream>>>(W_ih, b_ih, b_hh, WihP, biasL);
  cvt_f32_bf16<<<1024, 256, 0, stream>>>(W_hh, Whhb, 2048 * 512 / 4);
  cvt_f32_bf16<<<2048, 256, 0, stream>>>(W0, W0b, 2048 * 2048 / 4);
  cvt_f32_bf16<<<2048, 256, 0, stream>>>(W1, W1b, 2048 * 2048 / 4);
  gather_kernel<<<8192, 256, 0, stream>>>(prem, hyp, embed, Ain);
  // x_proj = combined @ W_ih^T + (b_ih + b_hh) : M=32768, N=2048, K=320
  gemm_pipe<128, 0><<<dim3(256, 16), 256, 0, stream>>>(Ain, WihP, biasL, xp, 320, 2048);
  (void)hipMemsetAsync(hA, 0, (size_t)1024 * 512 * 2, stream);  // h0 = 0 (aliases Ain)
  // persistent recurrence: 80KB dyn LDS; 256 wgs always co-resident
  (void)hipFuncSetAttribute(reinterpret_cast<const void*>(lstm_persist),
                            hipFuncAttributeMaxDynamicSharedMemorySize, 81920);
  lstm_persist<<<256, 256, 81920, stream>>>(xp, Whhb, hA, hB, ctr);
  feat_kernel<<<256, 256, 0, stream>>>(hA, feat);  // t=63 wrote hA
  bn_stats<<<8, 256, 0, stream>>>(feat, bn0g, bn0b, sc0, sh0);
  bn_apply<<<2048, 256, 0, stream>>>(feat, sc0, sh0, xn);
  gemm_pipe<64, 1><<<dim3(4, 16), 256, 0, stream>>>(xn, W0b, b0, x1, 2048, 2048);
  bn_stats<<<8, 256, 0, stream>>>(x1, bn1g, bn1b, sc1, sh1);
  bn_apply<<<2048, 256, 0, stream>>>(x1, sc1, sh1, xn);
  gemm_pipe<64, 1><<<dim3(4, 16), 256, 0, stream>>>(xn, W1b, b1, x2, 2048, 2048);
  bn_stats<<<8, 256, 0, stream>>>(x2, bnog, bnob, sc2, sh2);
  final_kernel<<<256, 256, 0, stream>>>(x2, sc2, sh2, Wo, bo, out);
}